// Round 15
// baseline (262.978 us; speedup 1.0000x reference)
//
#include <hip/hip_runtime.h>
#include <math.h>

#define NN 50000
#define NNP (NN + 1)          // +1 dummy zero row per slice
#define NE 800000
#define NEP 1150000           // NE + 7*NN upper bound on padded edge count
#define NBLK 49               // ceil(NN/1024)
#define NBKT 7                // dst-range buckets (d >> 13)
#define BCAP 262144           // per-bucket bin capacity
#define GEMMBLK 782           // (NN+63)/64
#define FILLBLK 448           // 7 buckets x 64 slices

typedef __attribute__((ext_vector_type(8))) short short8;
typedef __attribute__((ext_vector_type(4))) float float4v;

// bf16 helpers (RNE pack, shift unpack)
__device__ inline unsigned int f2bf(float f) {
  unsigned int u = __float_as_uint(f);
  return (u + 0x7fffu + ((u >> 16) & 1u)) >> 16;
}
__device__ inline unsigned int pack2bf(float lo, float hi) {
  return f2bf(lo) | (f2bf(hi) << 16);
}
__device__ inline float bflo(unsigned int p) { return __uint_as_float(p << 16); }
__device__ inline float bfhi(unsigned int p) { return __uint_as_float(p & 0xffff0000u); }

// BN finalize fold, shared by the fused GEMMs: 8-replica gstat -> (a, c) in LDS.
__device__ inline void bn_fold(const float* __restrict__ gstat, const float* __restrict__ g,
                               const float* __restrict__ be, float* __restrict__ bnabS, int tid) {
  if (tid < 128) {
    float s = 0.f, q = 0.f;
    #pragma unroll
    for (int r = 0; r < 8; r++) {
      s += gstat[r * 256 + tid];
      q += gstat[r * 256 + 128 + tid];
    }
    const float inv = 1.f / (float)NN;
    float m = s * inv;
    float var = q * inv - m * m;
    float a = rsqrtf(var + 1e-5f) * g[tid];
    bnabS[tid] = a;
    bnabS[128 + tid] = be[tid] - m * a;
  }
}

// ---------------- init: zero deg/gstat/binCnt, W->bf16^T prep ----------------

__global__ __launch_bounds__(256) void k_init(int* __restrict__ deg, float* __restrict__ gstat,
                                              int* __restrict__ binCnt,
                                              const float* __restrict__ W0, const float* __restrict__ W1,
                                              const float* __restrict__ W2,
                                              unsigned short* __restrict__ wt16) {
  int i = blockIdx.x * 256 + threadIdx.x;
  if (i < NN) deg[i] = 0;
  if (i < 4096) gstat[i] = 0.f;  // 2 layers x 8 reps x [sum128|sumsq128]
  if (i < NBKT) binCnt[i] = 0;
  if (i < 32768) {               // W0^T, W1^T bf16
    int w = i >> 14;
    int rem = i & 16383;
    int k = rem >> 7;
    int n = rem & 127;
    const float* W = w ? W1 : W0;
    wt16[w * 16384 + n * 128 + k] = (unsigned short)f2bf(W[k * 128 + n]);
  } else if (i < 36864) {        // W2^T bf16 (32x128)
    int idx = i - 32768;
    int n = idx >> 7;
    int k = idx & 127;
    wt16[32768 + n * 128 + k] = (unsigned short)f2bf(W2[k * 32 + n]);
  }
}

// ---------------- pass A: degree count + dst-range binning ----------------
// The deg atomicAdd's RETURN VALUE is the edge's per-dst rank -> packed into the
// bin entry (d in bits 0..15, rank in bits 16..31; NN < 2^16, max degree << 2^16).
// This lets the fill pass compute csr positions WITHOUT any atomics.
// Bucketing gives the csr scatter WRITE locality (R8: direct scatter = 16x
// write-allocate amplification).

__global__ __launch_bounds__(1024) void k_binA(const int* __restrict__ src, const int* __restrict__ dst,
                                               int* __restrict__ deg, int* __restrict__ binCnt,
                                               int2* __restrict__ bin) {
  __shared__ int lcnt[NBKT], lbase[NBKT];
  int tid = threadIdx.x;
  if (tid < NBKT) lcnt[tid] = 0;
  __syncthreads();
  int e = blockIdx.x * 1024 + tid;
  bool act = e < NE;
  int d = 0, s = 0, b = 0, rank = 0, drank = 0;
  if (act) {
    d = dst[e]; s = src[e];
    b = d >> 13;                       // 0..6
    drank = atomicAdd(&deg[d], 1);     // per-dst sequence number
    rank = atomicAdd(&lcnt[b], 1);
  }
  __syncthreads();
  if (tid < NBKT && lcnt[tid] > 0) lbase[tid] = atomicAdd(&binCnt[tid], lcnt[tid]);
  __syncthreads();
  if (act) bin[(size_t)b * BCAP + lbase[b] + rank] =
      make_int2((int)((unsigned)d | ((unsigned)drank << 16)), s);
}

// ---------------- scan1: padded-degree block scan (wave-shfl, 2 barriers) ----------------

__global__ __launch_bounds__(1024) void k_scan1(const int* __restrict__ deg, int* __restrict__ degtot,
                                                int* __restrict__ excl, int* __restrict__ blksum) {
  __shared__ int smW[16];
  int t = threadIdx.x;
  int i = blockIdx.x * 1024 + t;
  int wv = t >> 6, ln = t & 63;
  int tot = 0;
  if (i < NN) {
    tot = deg[i];
    degtot[i] = tot;
  }
  int v = (i < NN) ? ((tot + 7) & ~7) : 0;
  // wave inclusive scan
  int sc = v;
  #pragma unroll
  for (int off = 1; off < 64; off <<= 1) {
    int u = __shfl_up(sc, off);
    if (ln >= off) sc += u;
  }
  if (ln == 63) smW[wv] = sc;
  __syncthreads();
  if (t < 64) {
    int wsum = (t < 16) ? smW[t] : 0;
    int s2 = wsum;
    #pragma unroll
    for (int off = 1; off < 16; off <<= 1) {
      int u = __shfl_up(s2, off);
      if (t >= off) s2 += u;
    }
    if (t < 16) smW[t] = s2 - wsum;           // exclusive wave offsets
    if (t == 15) blksum[blockIdx.x] = s2;     // block total
  }
  __syncthreads();
  if (i < NN) excl[i] = (sc - v) + smW[wv];
}

// ---------------- scan3 (absorbs scan2): finalize rowstart; dis; pad zeroing ----------------

__global__ __launch_bounds__(256) void k_scan3(int* __restrict__ rowstart, const int* __restrict__ blksum,
                                               const int* __restrict__ degtot,
                                               float* __restrict__ dis,
                                               unsigned short* __restrict__ hs16, float* __restrict__ h2) {
  __shared__ int offS;
  int tid = threadIdx.x;
  int i = blockIdx.x * 256 + tid;
  int myblk = blockIdx.x >> 2;   // 256-chunk -> which 1024-block of scan1
  if (tid < 64) {
    int bv = (tid < NBLK) ? blksum[tid] : 0;
    int sc = bv;
    #pragma unroll
    for (int off = 1; off < 64; off <<= 1) {
      int u = __shfl_up(sc, off);
      if (tid >= off) sc += u;
    }
    int pre = (myblk > 0) ? __shfl(sc, myblk - 1) : 0;
    int total = __shfl(sc, NBLK - 1);
    if (tid == 0) {
      offS = pre;
      if (blockIdx.x == 0) rowstart[NN] = total;   // padded edge total
    }
  }
  __syncthreads();
  int boff = offS;
  if (i < NN) {
    rowstart[i] = rowstart[i] + boff;
    dis[i] = rsqrtf((float)degtot[i] + 1.0f);
  }
  if (i < 64) {   // hs16 pad row: 2 slices x 64 bf16 = 2 x 32 uints
    int slice = i >> 5, c = i & 31;
    ((unsigned int*)(hs16 + (size_t)slice * ((size_t)NNP * 64) + (size_t)NN * 64))[c] = 0u;
  }
  if (i < 32) h2[(size_t)NN * 32 + i] = 0.f;
}

// ---------------- fused: csr scatter (bucketed, ATOMIC-FREE) + layer-0 MFMA GEMM ----------------
// Fill decodes (d, rank) from the bin entry: position = rowstart[d] + rank.
// R10-proven spatial split: fill blocks first (temporally isolated from the GEMM
// generation's streaming traffic -> csr write locality preserved), GEMM after.
// R11's per-block epilogue interleaved scatter with streaming writes (+18 MB WRITE).

__global__ __launch_bounds__(256) void k_fillgemm(const int2* __restrict__ bin,
                                                  const int* __restrict__ binCnt,
                                                  const int* __restrict__ rowstart,
                                                  int* __restrict__ csr_src,
                                                  const float* __restrict__ X,
                                                  const unsigned short* __restrict__ Wt,
                                                  const float* __restrict__ dis,
                                                  unsigned short* __restrict__ hs16) {
  __shared__ char smem[52224];
  const int tid = threadIdx.x;

  if (blockIdx.x < FILLBLK) {
    // ---- fill part: no atomics, no LDS, no barriers ----
    int b = blockIdx.x % NBKT;
    int q = blockIdx.x / NBKT;   // 0..63
    int cnt = binCnt[b];
    const int2* __restrict__ B = bin + (size_t)b * BCAP;
    for (int i = q * 256 + tid; i < cnt; i += 64 * 256) {
      int2 ds = B[i];
      unsigned int v = (unsigned int)ds.x;
      int d = (int)(v & 0xffffu);
      int rank = (int)(v >> 16);
      csr_src[rowstart[d] + rank] = ds.y;
    }
    return;
  }

  // ---- GEMM part ----
  unsigned short* A  = (unsigned short*)smem;            // [64][136]
  unsigned short* Bt = (unsigned short*)(smem + 17408);  // [128][136]
  float* C = (float*)smem;                               // [64][132] (reuse after compute)
  const int row0 = (blockIdx.x - FILLBLK) * 64;
  const int M = NN;

  {
    int c4 = tid & 31;   // float4 col within row
    #pragma unroll
    for (int i = 0; i < 8; i++) {
      int r = (tid >> 5) + i * 8;
      int gr = row0 + r;
      float4 v = make_float4(0.f, 0.f, 0.f, 0.f);
      if (gr < M) v = *(const float4*)(X + (size_t)gr * 128 + c4 * 4);
      *(uint2*)(A + r * 136 + c4 * 4) = make_uint2(pack2bf(v.x, v.y), pack2bf(v.z, v.w));
    }
  }
  {
    int r = tid >> 1, h = (tid & 1) * 64;
    const uint4* src = (const uint4*)(Wt + r * 128 + h);
    uint4* dst = (uint4*)(Bt + r * 136 + h);
    #pragma unroll
    for (int i = 0; i < 8; i++) dst[i] = src[i];
  }
  __syncthreads();

  const int wv = tid >> 6;       // 0..3
  const int l = tid & 63;
  const int lm = l & 15;
  const int lq = l >> 4;

  float4v acc[8];
  #pragma unroll
  for (int j = 0; j < 8; j++) acc[j] = (float4v)(0.f);

  const unsigned short* Arow = A + (wv * 16 + lm) * 136 + lq * 8;
  #pragma unroll
  for (int ks = 0; ks < 4; ks++) {
    short8 af = *(const short8*)(Arow + ks * 32);
    #pragma unroll
    for (int j = 0; j < 8; j++) {
      short8 bf = *(const short8*)(Bt + (j * 16 + lm) * 136 + lq * 8 + ks * 32);
      acc[j] = __builtin_amdgcn_mfma_f32_16x16x32_bf16(af, bf, acc[j], 0, 0, 0);
    }
  }
  __syncthreads();   // done reading A/Bt; reuse as C

  #pragma unroll
  for (int j = 0; j < 8; j++) {
    int col = j * 16 + lm;
    int rbase = wv * 16 + lq * 4;
    #pragma unroll
    for (int r = 0; r < 4; r++) C[(rbase + r) * 132 + col] = acc[j][r];
  }
  __syncthreads();

  {
    #pragma unroll
    for (int i = 0; i < 4; i++) {
      int idx = tid + i * 256;
      int slice = idx >> 9;
      int r = (idx >> 3) & 63;
      int ch = idx & 7;
      int gr = row0 + r;
      if (gr < M) {
        float d = dis[gr];
        const float* cp = C + r * 132 + slice * 64 + ch * 8;
        uint4 u;
        u.x = pack2bf(cp[0] * d, cp[1] * d);
        u.y = pack2bf(cp[2] * d, cp[3] * d);
        u.z = pack2bf(cp[4] * d, cp[5] * d);
        u.w = pack2bf(cp[6] * d, cp[7] * d);
        *(uint4*)(hs16 + (size_t)slice * ((size_t)NNP * 64) + (size_t)gr * 64 + ch * 8) = u;
      }
    }
  }
}

// ---------------- MFMA GEMM 128->128 with fused BN(fold)/ReLU/residual input ----------------
// O is packed bf16 (128/row); Xin is fp32 (original x). Writes XA as bf16.

__global__ __launch_bounds__(256) void k_gemm128f(const unsigned short* __restrict__ O16,
                                                  const float* __restrict__ Xin,
                                                  unsigned short* __restrict__ XA16,
                                                  const float* __restrict__ gstat,
                                                  const float* __restrict__ g,
                                                  const float* __restrict__ be,
                                                  const unsigned short* __restrict__ Wt,
                                                  const float* __restrict__ dis,
                                                  unsigned short* __restrict__ hs16, int M) {
  __shared__ char smem[52224];
  __shared__ float bnabS[256];
  unsigned short* A  = (unsigned short*)smem;            // [64][136]
  unsigned short* Bt = (unsigned short*)(smem + 17408);  // [128][136]
  float* C = (float*)smem;                               // [64][132] (reuse after compute)
  const int tid = threadIdx.x;
  const int row0 = blockIdx.x * 64;

  bn_fold(gstat, g, be, bnabS, tid);
  __syncthreads();

  // stage A fused: thread t -> 8-feat chunk c=t&15, rows (t>>4)+i*16
  {
    int c = tid & 15;
    float4 alo = *(const float4*)(bnabS + c * 8);
    float4 ahi = *(const float4*)(bnabS + c * 8 + 4);
    float4 clo = *(const float4*)(bnabS + 128 + c * 8);
    float4 chi = *(const float4*)(bnabS + 128 + c * 8 + 4);
    #pragma unroll
    for (int i = 0; i < 4; i++) {
      int r = (tid >> 4) + i * 16;
      int gr = row0 + r;
      uint4 u = make_uint4(0u, 0u, 0u, 0u);
      if (gr < M) {
        uint4 ou = *(const uint4*)(O16 + (size_t)gr * 128 + c * 8);
        float4 xlo = *(const float4*)(Xin + (size_t)gr * 128 + c * 8);
        float4 xhi = *(const float4*)(Xin + (size_t)gr * 128 + c * 8 + 4);
        float v0 = fmaxf(bflo(ou.x) * alo.x + clo.x, 0.f) + xlo.x;
        float v1 = fmaxf(bfhi(ou.x) * alo.y + clo.y, 0.f) + xlo.y;
        float v2 = fmaxf(bflo(ou.y) * alo.z + clo.z, 0.f) + xlo.z;
        float v3 = fmaxf(bfhi(ou.y) * alo.w + clo.w, 0.f) + xlo.w;
        float v4 = fmaxf(bflo(ou.z) * ahi.x + chi.x, 0.f) + xhi.x;
        float v5 = fmaxf(bfhi(ou.z) * ahi.y + chi.y, 0.f) + xhi.y;
        float v6 = fmaxf(bflo(ou.w) * ahi.z + chi.z, 0.f) + xhi.z;
        float v7 = fmaxf(bfhi(ou.w) * ahi.w + chi.w, 0.f) + xhi.w;
        u.x = pack2bf(v0, v1);
        u.y = pack2bf(v2, v3);
        u.z = pack2bf(v4, v5);
        u.w = pack2bf(v6, v7);
        *(uint4*)(XA16 + (size_t)gr * 128 + c * 8) = u;
      }
      *(uint4*)(A + r * 136 + c * 8) = u;
    }
  }
  // stage Bt
  {
    int r = tid >> 1, h = (tid & 1) * 64;
    const uint4* src = (const uint4*)(Wt + r * 128 + h);
    uint4* dst = (uint4*)(Bt + r * 136 + h);
    #pragma unroll
    for (int i = 0; i < 8; i++) dst[i] = src[i];
  }
  __syncthreads();

  const int wv = tid >> 6;
  const int l = tid & 63;
  const int lm = l & 15;
  const int lq = l >> 4;

  float4v acc[8];
  #pragma unroll
  for (int j = 0; j < 8; j++) acc[j] = (float4v)(0.f);

  const unsigned short* Arow = A + (wv * 16 + lm) * 136 + lq * 8;
  #pragma unroll
  for (int ks = 0; ks < 4; ks++) {
    short8 af = *(const short8*)(Arow + ks * 32);
    #pragma unroll
    for (int j = 0; j < 8; j++) {
      short8 bf = *(const short8*)(Bt + (j * 16 + lm) * 136 + lq * 8 + ks * 32);
      acc[j] = __builtin_amdgcn_mfma_f32_16x16x32_bf16(af, bf, acc[j], 0, 0, 0);
    }
  }
  __syncthreads();

  #pragma unroll
  for (int j = 0; j < 8; j++) {
    int col = j * 16 + lm;
    int rbase = wv * 16 + lq * 4;
    #pragma unroll
    for (int r = 0; r < 4; r++) C[(rbase + r) * 132 + col] = acc[j][r];
  }
  __syncthreads();

  // pack-out: wave-linear
  {
    #pragma unroll
    for (int i = 0; i < 4; i++) {
      int idx = tid + i * 256;
      int slice = idx >> 9;
      int r = (idx >> 3) & 63;
      int ch = idx & 7;
      int gr = row0 + r;
      if (gr < M) {
        float d = dis[gr];
        const float* cp = C + r * 132 + slice * 64 + ch * 8;
        uint4 u;
        u.x = pack2bf(cp[0] * d, cp[1] * d);
        u.y = pack2bf(cp[2] * d, cp[3] * d);
        u.z = pack2bf(cp[4] * d, cp[5] * d);
        u.w = pack2bf(cp[6] * d, cp[7] * d);
        *(uint4*)(hs16 + (size_t)slice * ((size_t)NNP * 64) + (size_t)gr * 64 + ch * 8) = u;
      }
    }
  }
}

// ---------------- MFMA bf16 GEMM 128->32 with fused BN(fold)/ReLU/residual input ----------------

__global__ __launch_bounds__(256) void k_gemm32mf(const unsigned short* __restrict__ O16,
                                                  const unsigned short* __restrict__ XA16,
                                                  const float* __restrict__ gstat,
                                                  const float* __restrict__ g,
                                                  const float* __restrict__ be,
                                                  const unsigned short* __restrict__ Wt2,
                                                  const float* __restrict__ dis,
                                                  float* __restrict__ H, int M) {
  __shared__ char smem[26112];
  __shared__ float bnabS[256];
  unsigned short* A   = (unsigned short*)smem;            // [64][136]
  unsigned short* Bt2 = (unsigned short*)(smem + 17408);  // [32][136]
  float* C = (float*)smem;                                // [64][36] (reuse)
  const int tid = threadIdx.x;
  const int row0 = blockIdx.x * 64;

  bn_fold(gstat, g, be, bnabS, tid);
  __syncthreads();

  // stage A fused: bf16 O + bf16 residual
  {
    int c = tid & 15;
    float4 alo = *(const float4*)(bnabS + c * 8);
    float4 ahi = *(const float4*)(bnabS + c * 8 + 4);
    float4 clo = *(const float4*)(bnabS + 128 + c * 8);
    float4 chi = *(const float4*)(bnabS + 128 + c * 8 + 4);
    #pragma unroll
    for (int i = 0; i < 4; i++) {
      int r = (tid >> 4) + i * 16;
      int gr = row0 + r;
      uint4 u = make_uint4(0u, 0u, 0u, 0u);
      if (gr < M) {
        uint4 ou = *(const uint4*)(O16 + (size_t)gr * 128 + c * 8);
        uint4 xu = *(const uint4*)(XA16 + (size_t)gr * 128 + c * 8);
        float v0 = fmaxf(bflo(ou.x) * alo.x + clo.x, 0.f) + bflo(xu.x);
        float v1 = fmaxf(bfhi(ou.x) * alo.y + clo.y, 0.f) + bfhi(xu.x);
        float v2 = fmaxf(bflo(ou.y) * alo.z + clo.z, 0.f) + bflo(xu.y);
        float v3 = fmaxf(bfhi(ou.y) * alo.w + clo.w, 0.f) + bfhi(xu.y);
        float v4 = fmaxf(bflo(ou.z) * ahi.x + chi.x, 0.f) + bflo(xu.z);
        float v5 = fmaxf(bfhi(ou.z) * ahi.y + chi.y, 0.f) + bfhi(xu.z);
        float v6 = fmaxf(bflo(ou.w) * ahi.z + chi.z, 0.f) + bflo(xu.w);
        float v7 = fmaxf(bfhi(ou.w) * ahi.w + chi.w, 0.f) + bfhi(xu.w);
        u.x = pack2bf(v0, v1);
        u.y = pack2bf(v2, v3);
        u.z = pack2bf(v4, v5);
        u.w = pack2bf(v6, v7);
      }
      *(uint4*)(A + r * 136 + c * 8) = u;
    }
  }
  // stage Bt2: thread t -> row t>>3 (0..31), 16 bf16 at (t&7)*16 = 2 x uint4
  {
    int r = tid >> 3, h = (tid & 7) * 16;
    const uint4* src = (const uint4*)(Wt2 + r * 128 + h);
    uint4* dst = (uint4*)(Bt2 + r * 136 + h);
    dst[0] = src[0];
    dst[1] = src[1];
  }
  __syncthreads();

  const int wv = tid >> 6;
  const int l = tid & 63;
  const int lm = l & 15;
  const int lq = l >> 4;

  float4v acc[2];
  acc[0] = (float4v)(0.f);
  acc[1] = (float4v)(0.f);

  const unsigned short* Arow = A + (wv * 16 + lm) * 136 + lq * 8;
  #pragma unroll
  for (int ks = 0; ks < 4; ks++) {
    short8 af = *(const short8*)(Arow + ks * 32);
    #pragma unroll
    for (int j = 0; j < 2; j++) {
      short8 bf = *(const short8*)(Bt2 + (j * 16 + lm) * 136 + lq * 8 + ks * 32);
      acc[j] = __builtin_amdgcn_mfma_f32_16x16x32_bf16(af, bf, acc[j], 0, 0, 0);
    }
  }
  __syncthreads();   // reuse smem as C

  #pragma unroll
  for (int j = 0; j < 2; j++) {
    int col = j * 16 + lm;
    int rbase = wv * 16 + lq * 4;
    #pragma unroll
    for (int r = 0; r < 4; r++) C[(rbase + r) * 36 + col] = acc[j][r];
  }
  __syncthreads();

  // pack-out: wave-linear float4 over [64 rows][8 float4]
  {
    #pragma unroll
    for (int i = 0; i < 2; i++) {
      int idx = tid + i * 256;
      int r = idx >> 3;
      int ch = idx & 7;
      int gr = row0 + r;
      if (gr < M) {
        float d = dis[gr];
        const float* cp = C + r * 36 + ch * 4;
        float4 v = make_float4(cp[0] * d, cp[1] * d, cp[2] * d, cp[3] * d);
        *(float4*)(H + (size_t)gr * 32 + ch * 4) = v;
      }
    }
  }
}

// ---------------- aggregation layer 0/1: both slices per wave, 8 nodes/wave ----------------
// R5-proven shape: 16 gathers in flight per lane, csr prefetched one iteration
// ahead, low-VGPR class (do NOT unroll 2x: R6 showed 132 VGPR -> occupancy collapse).
// Padding handled by degtot masking: positions >= e0+deg redirect to zero pad row NN.
// Output packed bf16. Fused BN stats via LDS + 8-way replicated atomics.

__global__ __launch_bounds__(256) void k_agg128s(const unsigned short* __restrict__ Hs,
                                                 const float* __restrict__ dis,
                                                 const int* __restrict__ rowstart,
                                                 const int* __restrict__ degtot,
                                                 const int* __restrict__ csr_src,
                                                 const float* __restrict__ bias,
                                                 unsigned short* __restrict__ out16,
                                                 float* __restrict__ gstat) {
  __shared__ float smS[4][128], smQ[4][128];
  const int tid = threadIdx.x;
  const int wv = tid >> 6;
  const int lane = tid & 63;
  const int node_sub = lane >> 3;   // 0..7
  const int fl = lane & 7;          // 0..7 (8 bf16 = 16 B each)
  const int base = node_sub * 8;
  const int w = blockIdx.x * 32 + wv * 8 + node_sub;
  const bool act = w < NN;
  const unsigned short* __restrict__ S0 = Hs + fl * 8;
  const unsigned short* __restrict__ S1 = Hs + (size_t)NNP * 64 + fl * 8;
  float di = act ? dis[w] : 0.f;
  int e0 = 0, e1 = 0, dend = 0;
  if (act) { e0 = rowstart[w]; e1 = rowstart[w + 1]; dend = e0 + degtot[w]; }

  float a0[8], a1[8];
  #pragma unroll
  for (int j = 0; j < 8; j++) { a0[j] = 0.f; a1[j] = 0.f; }

  int idxCur = (e0 < e1) ? csr_src[e0 + fl] : 0;
  for (int e = e0; e < e1; e += 8) {
    int cur = (e + fl < dend) ? idxCur : (int)NN;   // pad -> zero row
    if (e + 8 < e1) idxCur = csr_src[e + 8 + fl];
    int s0 = __shfl(cur, base + 0), s1 = __shfl(cur, base + 1);
    int s2 = __shfl(cur, base + 2), s3 = __shfl(cur, base + 3);
    int s4 = __shfl(cur, base + 4), s5 = __shfl(cur, base + 5);
    int s6 = __shfl(cur, base + 6), s7 = __shfl(cur, base + 7);
    uint4 g0 = *(const uint4*)(S0 + (size_t)s0 * 64);
    uint4 g1 = *(const uint4*)(S0 + (size_t)s1 * 64);
    uint4 g2 = *(const uint4*)(S0 + (size_t)s2 * 64);
    uint4 g3 = *(const uint4*)(S0 + (size_t)s3 * 64);
    uint4 g4 = *(const uint4*)(S0 + (size_t)s4 * 64);
    uint4 g5 = *(const uint4*)(S0 + (size_t)s5 * 64);
    uint4 g6 = *(const uint4*)(S0 + (size_t)s6 * 64);
    uint4 g7 = *(const uint4*)(S0 + (size_t)s7 * 64);
    uint4 h0 = *(const uint4*)(S1 + (size_t)s0 * 64);
    uint4 h1 = *(const uint4*)(S1 + (size_t)s1 * 64);
    uint4 h2 = *(const uint4*)(S1 + (size_t)s2 * 64);
    uint4 h3 = *(const uint4*)(S1 + (size_t)s3 * 64);
    uint4 h4 = *(const uint4*)(S1 + (size_t)s4 * 64);
    uint4 h5 = *(const uint4*)(S1 + (size_t)s5 * 64);
    uint4 h6 = *(const uint4*)(S1 + (size_t)s6 * 64);
    uint4 h7 = *(const uint4*)(S1 + (size_t)s7 * 64);
    a0[0] += ((bflo(g0.x) + bflo(g1.x)) + (bflo(g2.x) + bflo(g3.x))) + ((bflo(g4.x) + bflo(g5.x)) + (bflo(g6.x) + bflo(g7.x)));
    a0[1] += ((bfhi(g0.x) + bfhi(g1.x)) + (bfhi(g2.x) + bfhi(g3.x))) + ((bfhi(g4.x) + bfhi(g5.x)) + (bfhi(g6.x) + bfhi(g7.x)));
    a0[2] += ((bflo(g0.y) + bflo(g1.y)) + (bflo(g2.y) + bflo(g3.y))) + ((bflo(g4.y) + bflo(g5.y)) + (bflo(g6.y) + bflo(g7.y)));
    a0[3] += ((bfhi(g0.y) + bfhi(g1.y)) + (bfhi(g2.y) + bfhi(g3.y))) + ((bfhi(g4.y) + bfhi(g5.y)) + (bfhi(g6.y) + bfhi(g7.y)));
    a0[4] += ((bflo(g0.z) + bflo(g1.z)) + (bflo(g2.z) + bflo(g3.z))) + ((bflo(g4.z) + bflo(g5.z)) + (bflo(g6.z) + bflo(g7.z)));
    a0[5] += ((bfhi(g0.z) + bfhi(g1.z)) + (bfhi(g2.z) + bfhi(g3.z))) + ((bfhi(g4.z) + bfhi(g5.z)) + (bfhi(g6.z) + bfhi(g7.z)));
    a0[6] += ((bflo(g0.w) + bflo(g1.w)) + (bflo(g2.w) + bflo(g3.w))) + ((bflo(g4.w) + bflo(g5.w)) + (bflo(g6.w) + bflo(g7.w)));
    a0[7] += ((bfhi(g0.w) + bfhi(g1.w)) + (bfhi(g2.w) + bfhi(g3.w))) + ((bfhi(g4.w) + bfhi(g5.w)) + (bfhi(g6.w) + bfhi(g7.w)));
    a1[0] += ((bflo(h0.x) + bflo(h1.x)) + (bflo(h2.x) + bflo(h3.x))) + ((bflo(h4.x) + bflo(h5.x)) + (bflo(h6.x) + bflo(h7.x)));
    a1[1] += ((bfhi(h0.x) + bfhi(h1.x)) + (bfhi(h2.x) + bfhi(h3.x))) + ((bfhi(h4.x) + bfhi(h5.x)) + (bfhi(h6.x) + bfhi(h7.x)));
    a1[2] += ((bflo(h0.y) + bflo(h1.y)) + (bflo(h2.y) + bflo(h3.y))) + ((bflo(h4.y) + bflo(h5.y)) + (bflo(h6.y) + bflo(h7.y)));
    a1[3] += ((bfhi(h0.y) + bfhi(h1.y)) + (bfhi(h2.y) + bfhi(h3.y))) + ((bfhi(h4.y) + bfhi(h5.y)) + (bfhi(h6.y) + bfhi(h7.y)));
    a1[4] += ((bflo(h0.z) + bflo(h1.z)) + (bflo(h2.z) + bflo(h3.z))) + ((bflo(h4.z) + bflo(h5.z)) + (bflo(h6.z) + bflo(h7.z)));
    a1[5] += ((bfhi(h0.z) + bfhi(h1.z)) + (bfhi(h2.z) + bfhi(h3.z))) + ((bfhi(h4.z) + bfhi(h5.z)) + (bfhi(h6.z) + bfhi(h7.z)));
    a1[6] += ((bflo(h0.w) + bflo(h1.w)) + (bflo(h2.w) + bflo(h3.w))) + ((bflo(h4.w) + bflo(h5.w)) + (bflo(h6.w) + bflo(h7.w)));
    a1[7] += ((bfhi(h0.w) + bfhi(h1.w)) + (bfhi(h2.w) + bfhi(h3.w))) + ((bfhi(h4.w) + bfhi(h5.w)) + (bfhi(h6.w) + bfhi(h7.w)));
  }

  float rv0[8], rv1[8];
  if (act) {
    uint4 sv0 = *(const uint4*)(S0 + (size_t)w * 64);
    uint4 sv1 = *(const uint4*)(S1 + (size_t)w * 64);
    float se0[8] = { bflo(sv0.x), bfhi(sv0.x), bflo(sv0.y), bfhi(sv0.y),
                     bflo(sv0.z), bfhi(sv0.z), bflo(sv0.w), bfhi(sv0.w) };
    float se1[8] = { bflo(sv1.x), bfhi(sv1.x), bflo(sv1.y), bfhi(sv1.y),
                     bflo(sv1.z), bfhi(sv1.z), bflo(sv1.w), bfhi(sv1.w) };
    #pragma unroll
    for (int j = 0; j < 8; j++) {
      rv0[j] = (a0[j] + se0[j]) * di + bias[fl * 8 + j];
      rv1[j] = (a1[j] + se1[j]) * di + bias[64 + fl * 8 + j];
    }
    uint4 u0, u1;
    u0.x = pack2bf(rv0[0], rv0[1]); u0.y = pack2bf(rv0[2], rv0[3]);
    u0.z = pack2bf(rv0[4], rv0[5]); u0.w = pack2bf(rv0[6], rv0[7]);
    u1.x = pack2bf(rv1[0], rv1[1]); u1.y = pack2bf(rv1[2], rv1[3]);
    u1.z = pack2bf(rv1[4], rv1[5]); u1.w = pack2bf(rv1[6], rv1[7]);
    *(uint4*)(out16 + (size_t)w * 128 + fl * 8)      = u0;
    *(uint4*)(out16 + (size_t)w * 128 + 64 + fl * 8) = u1;
  } else {
    #pragma unroll
    for (int j = 0; j < 8; j++) { rv0[j] = 0.f; rv1[j] = 0.f; }
  }

  // fused BN stats: reduce over node_sub (lane bits 3..5), then cross-wave via LDS
  float q0[8], q1[8];
  #pragma unroll
  for (int j = 0; j < 8; j++) { q0[j] = rv0[j] * rv0[j]; q1[j] = rv1[j] * rv1[j]; }
  #pragma unroll
  for (int off = 8; off <= 32; off <<= 1) {
    #pragma unroll
    for (int j = 0; j < 8; j++) {
      rv0[j] += __shfl_xor(rv0[j], off);
      q0[j]  += __shfl_xor(q0[j], off);
      rv1[j] += __shfl_xor(rv1[j], off);
      q1[j]  += __shfl_xor(q1[j], off);
    }
  }
  if (node_sub == 0) {
    #pragma unroll
    for (int j = 0; j < 8; j++) {
      smS[wv][fl * 8 + j] = rv0[j];      smQ[wv][fl * 8 + j] = q0[j];
      smS[wv][64 + fl * 8 + j] = rv1[j]; smQ[wv][64 + fl * 8 + j] = q1[j];
    }
  }
  __syncthreads();
  if (tid < 128) {
    float s = (smS[0][tid] + smS[1][tid]) + (smS[2][tid] + smS[3][tid]);
    float q = (smQ[0][tid] + smQ[1][tid]) + (smQ[2][tid] + smQ[3][tid]);
    int rep = blockIdx.x & 7;
    atomicAdd(&gstat[rep * 256 + tid], s);
    atomicAdd(&gstat[rep * 256 + 128 + tid], q);
  }
}

// ---------------- final layer: aggregation + fused log_softmax (fp32) ----------------
// Same degtot masking for padding.

__global__ __launch_bounds__(256) void k_agg32lsm(const float* __restrict__ H2,
                                                  const float* __restrict__ dis,
                                                  const int* __restrict__ rowstart,
                                                  const int* __restrict__ degtot,
                                                  const int* __restrict__ csr_src,
                                                  const float* __restrict__ bias,
                                                  float* __restrict__ out) {
  int wave = (blockIdx.x * 256 + threadIdx.x) >> 6;
  int lane = threadIdx.x & 63;
  int half = lane >> 5;
  int l = lane & 31;
  int hbase = half * 32;
  int w = wave * 2 + half;
  if (w >= NN) return;   // NN even: both halves exit together
  const float* __restrict__ S = H2 + l;
  float di = dis[w];
  int e0 = rowstart[w], e1 = rowstart[w + 1];
  int dend = e0 + degtot[w];
  float acc = 0.f;
  for (int e = e0; e < e1; e += 8) {
    int myIdx = csr_src[e + (l & 7)];
    if (e + (l & 7) >= dend) myIdx = NN;   // pad -> zero row
    int s0 = __shfl(myIdx, hbase + 0), s1 = __shfl(myIdx, hbase + 1);
    int s2 = __shfl(myIdx, hbase + 2), s3 = __shfl(myIdx, hbase + 3);
    int s4 = __shfl(myIdx, hbase + 4), s5 = __shfl(myIdx, hbase + 5);
    int s6 = __shfl(myIdx, hbase + 6), s7 = __shfl(myIdx, hbase + 7);
    float h0 = S[(size_t)s0 * 32], h1 = S[(size_t)s1 * 32];
    float h2v = S[(size_t)s2 * 32], h3 = S[(size_t)s3 * 32];
    float h4 = S[(size_t)s4 * 32], h5 = S[(size_t)s5 * 32];
    float h6 = S[(size_t)s6 * 32], h7 = S[(size_t)s7 * 32];
    acc += ((h0 + h1) + (h2v + h3)) + ((h4 + h5) + (h6 + h7));
  }
  float v = (acc + S[(size_t)w * 32]) * di + bias[l];
  float m = v;
  #pragma unroll
  for (int off = 16; off >= 1; off >>= 1) m = fmaxf(m, __shfl_xor(m, off));
  float ex = expf(v - m);
  float s = ex;
  #pragma unroll
  for (int off = 16; off >= 1; off >>= 1) s += __shfl_xor(s, off);
  out[(size_t)w * 32 + l] = v - m - logf(s);
}

// ---------------- launch ----------------

extern "C" void kernel_launch(void* const* d_in, const int* in_sizes, int n_in,
                              void* d_out, int out_size, void* d_ws, size_t ws_size,
                              hipStream_t stream) {
  const float* x   = (const float*)d_in[0];
  const int*   ei  = (const int*)d_in[1];
  const float* W0  = (const float*)d_in[2];
  const float* b0  = (const float*)d_in[3];
  const float* g0  = (const float*)d_in[4];
  const float* be0 = (const float*)d_in[5];
  const float* W1  = (const float*)d_in[6];
  const float* b1  = (const float*)d_in[7];
  const float* g1  = (const float*)d_in[8];
  const float* be1 = (const float*)d_in[9];
  const float* W2  = (const float*)d_in[10];
  const float* b2  = (const float*)d_in[11];
  float* out = (float*)d_out;
  const int* srcI = ei;
  const int* dstI = ei + NE;

  char* p = (char*)d_ws;
  auto take = [&](size_t bytes) { char* r = p; p += (bytes + 255) & ~(size_t)255; return (void*)r; };
  int*   deg      = (int*)take(NN * 4);
  int*   degtot   = (int*)take(NN * 4);
  int*   rowstart = (int*)take((NN + 1) * 4);
  int*   blksum   = (int*)take(64 * 4);
  int*   binCnt   = (int*)take(8 * 4);
  float* dis      = (float*)take(NN * 4);
  int*   csr      = (int*)take((size_t)NEP * 4);
  int2*  bin      = (int2*)take((size_t)NBKT * BCAP * 8);
  float* gstat    = (float*)take(4096 * 4);  // 2 layers x 8 reps x 256
  unsigned short* wt16 = (unsigned short*)take((2 * 16384 + 4096) * 2);  // W0^T, W1^T, W2^T bf16
  unsigned short* hs16 = (unsigned short*)take((size_t)NNP * 128 * 2);   // bf16, 2-slice-major
  unsigned short* o16  = (unsigned short*)take((size_t)NN * 128 * 2);    // agg output, packed bf16
  unsigned short* xA16 = (unsigned short*)take((size_t)NN * 128 * 2);    // layer-1 input, packed bf16
  float* h2       = (float*)take((size_t)NNP * 32 * 4);

  k_init<<<(NN + 255) / 256, 256, 0, stream>>>(deg, gstat, binCnt, W0, W1, W2, wt16);
  k_binA<<<(NE + 1023) / 1024, 1024, 0, stream>>>(srcI, dstI, deg, binCnt, bin);
  k_scan1<<<NBLK, 1024, 0, stream>>>(deg, degtot, rowstart, blksum);
  k_scan3<<<(NN + 255) / 256, 256, 0, stream>>>(rowstart, blksum, degtot, dis, hs16, h2);

  const int aggGrid = (NN + 31) / 32;   // 8 nodes/wave, both slices, 4 waves/block
  const int aggGrid32 = (NN + 7) / 8;   // 2 nodes/wave

  // ---- layer 0: atomic-free csr scatter + GEMM in one dispatch (spatial split) ----
  k_fillgemm<<<FILLBLK + GEMMBLK, 256, 0, stream>>>(bin, binCnt, rowstart, csr, x, wt16, dis, hs16);
  k_agg128s<<<aggGrid, 256, 0, stream>>>(hs16, dis, rowstart, degtot, csr, b0, o16, gstat);

  // ---- layer 1 (BN finalize + BN/ReLU/residual fused into GEMM stage-A) ----
  k_gemm128f<<<(NN + 63) / 64, 256, 0, stream>>>(o16, x, xA16, gstat, g0, be0,
                                                 wt16 + 16384, dis, hs16, NN);
  k_agg128s<<<aggGrid, 256, 0, stream>>>(hs16, dis, rowstart, degtot, csr, b1, o16, gstat + 2048);

  // ---- final conv (BN finalize + fuse in-kernel, xB never materialized) ----
  k_gemm32mf<<<(NN + 63) / 64, 256, 0, stream>>>(o16, xA16, gstat + 2048, g1, be1,
                                                 wt16 + 32768, dis, h2, NN);
  k_agg32lsm<<<aggGrid32, 256, 0, stream>>>(h2, dis, rowstart, degtot, csr, b2, out);
}

// Round 16
// 257.891 us; speedup vs baseline: 1.0197x; 1.0197x over previous
//
#include <hip/hip_runtime.h>
#include <math.h>

#define NN 50000
#define NNP (NN + 1)          // +1 dummy zero row per slice
#define NE 800000
#define NEP 1150000           // NE + 7*NN upper bound on padded edge count
#define NBLK 49               // ceil(NN/1024)
#define NBKT 7                // dst-range buckets (d >> 13)
#define BCAP 262144           // per-bucket bin capacity
#define GEMMBLK 782           // (NN+63)/64
#define FILLBLK 512

typedef __attribute__((ext_vector_type(8))) short short8;
typedef __attribute__((ext_vector_type(4))) float float4v;

// bf16 helpers (RNE pack, shift unpack)
__device__ inline unsigned int f2bf(float f) {
  unsigned int u = __float_as_uint(f);
  return (u + 0x7fffu + ((u >> 16) & 1u)) >> 16;
}
__device__ inline unsigned int pack2bf(float lo, float hi) {
  return f2bf(lo) | (f2bf(hi) << 16);
}
__device__ inline float bflo(unsigned int p) { return __uint_as_float(p << 16); }
__device__ inline float bfhi(unsigned int p) { return __uint_as_float(p & 0xffff0000u); }

// BN finalize fold, shared by the fused GEMMs: 8-replica gstat -> (a, c) in LDS.
__device__ inline void bn_fold(const float* __restrict__ gstat, const float* __restrict__ g,
                               const float* __restrict__ be, float* __restrict__ bnabS, int tid) {
  if (tid < 128) {
    float s = 0.f, q = 0.f;
    #pragma unroll
    for (int r = 0; r < 8; r++) {
      s += gstat[r * 256 + tid];
      q += gstat[r * 256 + 128 + tid];
    }
    const float inv = 1.f / (float)NN;
    float m = s * inv;
    float var = q * inv - m * m;
    float a = rsqrtf(var + 1e-5f) * g[tid];
    bnabS[tid] = a;
    bnabS[128 + tid] = be[tid] - m * a;
  }
}

// ---------------- init: zero deg/gstat/binCnt, W->bf16^T prep ----------------

__global__ __launch_bounds__(256) void k_init(int* __restrict__ deg, float* __restrict__ gstat,
                                              int* __restrict__ binCnt,
                                              const float* __restrict__ W0, const float* __restrict__ W1,
                                              const float* __restrict__ W2,
                                              unsigned short* __restrict__ wt16) {
  int i = blockIdx.x * 256 + threadIdx.x;
  if (i < NN) deg[i] = 0;
  if (i < 4096) gstat[i] = 0.f;  // 2 layers x 8 reps x [sum128|sumsq128]
  if (i < NBKT) binCnt[i] = 0;
  if (i < 32768) {               // W0^T, W1^T bf16
    int w = i >> 14;
    int rem = i & 16383;
    int k = rem >> 7;
    int n = rem & 127;
    const float* W = w ? W1 : W0;
    wt16[w * 16384 + n * 128 + k] = (unsigned short)f2bf(W[k * 128 + n]);
  } else if (i < 36864) {        // W2^T bf16 (32x128)
    int idx = i - 32768;
    int n = idx >> 7;
    int k = idx & 127;
    wt16[32768 + n * 128 + k] = (unsigned short)f2bf(W2[k * 32 + n]);
  }
}

// ---------------- pass A: degree count + dst-range binning ----------------
// The deg atomicAdd's RETURN VALUE is the edge's per-dst rank -> packed into the
// bin entry (d in bits 0..15, rank in bits 16..31; NN < 2^16, max degree << 2^16).
// This lets the fill pass compute csr positions WITHOUT any atomics.
// Bucketing gives the csr scatter WRITE locality (R8: direct scatter = 16x
// write-allocate amplification).

__global__ __launch_bounds__(1024) void k_binA(const int* __restrict__ src, const int* __restrict__ dst,
                                               int* __restrict__ deg, int* __restrict__ binCnt,
                                               int2* __restrict__ bin) {
  __shared__ int lcnt[NBKT], lbase[NBKT];
  int tid = threadIdx.x;
  if (tid < NBKT) lcnt[tid] = 0;
  __syncthreads();
  int e = blockIdx.x * 1024 + tid;
  bool act = e < NE;
  int d = 0, s = 0, b = 0, rank = 0, drank = 0;
  if (act) {
    d = dst[e]; s = src[e];
    b = d >> 13;                       // 0..6
    drank = atomicAdd(&deg[d], 1);     // per-dst sequence number
    rank = atomicAdd(&lcnt[b], 1);
  }
  __syncthreads();
  if (tid < NBKT && lcnt[tid] > 0) lbase[tid] = atomicAdd(&binCnt[tid], lcnt[tid]);
  __syncthreads();
  if (act) bin[(size_t)b * BCAP + lbase[b] + rank] =
      make_int2((int)((unsigned)d | ((unsigned)drank << 16)), s);
}

// ---------------- scan1: padded-degree block scan (wave-shfl, 2 barriers) ----------------

__global__ __launch_bounds__(1024) void k_scan1(const int* __restrict__ deg, int* __restrict__ degtot,
                                                int* __restrict__ excl, int* __restrict__ blksum) {
  __shared__ int smW[16];
  int t = threadIdx.x;
  int i = blockIdx.x * 1024 + t;
  int wv = t >> 6, ln = t & 63;
  int tot = 0;
  if (i < NN) {
    tot = deg[i];
    degtot[i] = tot;
  }
  int v = (i < NN) ? ((tot + 7) & ~7) : 0;
  // wave inclusive scan
  int sc = v;
  #pragma unroll
  for (int off = 1; off < 64; off <<= 1) {
    int u = __shfl_up(sc, off);
    if (ln >= off) sc += u;
  }
  if (ln == 63) smW[wv] = sc;
  __syncthreads();
  if (t < 64) {
    int wsum = (t < 16) ? smW[t] : 0;
    int s2 = wsum;
    #pragma unroll
    for (int off = 1; off < 16; off <<= 1) {
      int u = __shfl_up(s2, off);
      if (t >= off) s2 += u;
    }
    if (t < 16) smW[t] = s2 - wsum;           // exclusive wave offsets
    if (t == 15) blksum[blockIdx.x] = s2;     // block total
  }
  __syncthreads();
  if (i < NN) excl[i] = (sc - v) + smW[wv];
}

// ---------------- scan3 (absorbs scan2): finalize rowstart; dis; pad zeroing ----------------

__global__ __launch_bounds__(256) void k_scan3(int* __restrict__ rowstart, const int* __restrict__ blksum,
                                               const int* __restrict__ degtot,
                                               float* __restrict__ dis,
                                               unsigned short* __restrict__ hs16, float* __restrict__ h2) {
  __shared__ int offS;
  int tid = threadIdx.x;
  int i = blockIdx.x * 256 + tid;
  int myblk = blockIdx.x >> 2;   // 256-chunk -> which 1024-block of scan1
  if (tid < 64) {
    int bv = (tid < NBLK) ? blksum[tid] : 0;
    int sc = bv;
    #pragma unroll
    for (int off = 1; off < 64; off <<= 1) {
      int u = __shfl_up(sc, off);
      if (tid >= off) sc += u;
    }
    int pre = (myblk > 0) ? __shfl(sc, myblk - 1) : 0;
    int total = __shfl(sc, NBLK - 1);
    if (tid == 0) {
      offS = pre;
      if (blockIdx.x == 0) rowstart[NN] = total;   // padded edge total
    }
  }
  __syncthreads();
  int boff = offS;
  if (i < NN) {
    rowstart[i] = rowstart[i] + boff;
    dis[i] = rsqrtf((float)degtot[i] + 1.0f);
  }
  if (i < 64) {   // hs16 pad row: 2 slices x 64 bf16 = 2 x 32 uints
    int slice = i >> 5, c = i & 31;
    ((unsigned int*)(hs16 + (size_t)slice * ((size_t)NNP * 64) + (size_t)NN * 64))[c] = 0u;
  }
  if (i < 32) h2[(size_t)NN * 32 + i] = 0.f;
}

// ---------------- fused: csr scatter (bucketed, ATOMIC-FREE) + layer-0 MFMA GEMM ----------------
// Fill decodes (d, rank) from the bin entry: position = rowstart[d] + rank.
// R10-proven spatial split: fill blocks first (temporally isolated from the GEMM
// generation's streaming traffic -> csr write locality preserved), GEMM after.
// R11's per-block epilogue interleaved scatter with streaming writes (+18 MB WRITE).

__global__ __launch_bounds__(256) void k_fillgemm(const int2* __restrict__ bin,
                                                  const int* __restrict__ binCnt,
                                                  const int* __restrict__ rowstart,
                                                  int* __restrict__ csr_src,
                                                  const float* __restrict__ X,
                                                  const unsigned short* __restrict__ Wt,
                                                  const float* __restrict__ dis,
                                                  unsigned short* __restrict__ hs16) {
  __shared__ char smem[52224];
  const int tid = threadIdx.x;

  if (blockIdx.x < FILLBLK) {
    // ---- fill part: no atomics, no LDS, no barriers ----
    int bb = blockIdx.x;
    int b = bb & 7;
    if (b >= NBKT) return;
    int q = bb >> 3;             // 0..63
    int cnt = binCnt[b];
    const int2* __restrict__ B = bin + (size_t)b * BCAP;
    for (int i = q * 256 + tid; i < cnt; i += 64 * 256) {
      int2 ds = B[i];
      unsigned int v = (unsigned int)ds.x;
      int d = (int)(v & 0xffffu);
      int rank = (int)(v >> 16);
      csr_src[rowstart[d] + rank] = ds.y;
    }
    return;
  }

  // ---- GEMM part ----
  unsigned short* A  = (unsigned short*)smem;            // [64][136]
  unsigned short* Bt = (unsigned short*)(smem + 17408);  // [128][136]
  float* C = (float*)smem;                               // [64][132] (reuse after compute)
  const int row0 = (blockIdx.x - FILLBLK) * 64;
  const int M = NN;

  {
    int c4 = tid & 31;   // float4 col within row
    #pragma unroll
    for (int i = 0; i < 8; i++) {
      int r = (tid >> 5) + i * 8;
      int gr = row0 + r;
      float4 v = make_float4(0.f, 0.f, 0.f, 0.f);
      if (gr < M) v = *(const float4*)(X + (size_t)gr * 128 + c4 * 4);
      *(uint2*)(A + r * 136 + c4 * 4) = make_uint2(pack2bf(v.x, v.y), pack2bf(v.z, v.w));
    }
  }
  {
    int r = tid >> 1, h = (tid & 1) * 64;
    const uint4* src = (const uint4*)(Wt + r * 128 + h);
    uint4* dst = (uint4*)(Bt + r * 136 + h);
    #pragma unroll
    for (int i = 0; i < 8; i++) dst[i] = src[i];
  }
  __syncthreads();

  const int wv = tid >> 6;       // 0..3
  const int l = tid & 63;
  const int lm = l & 15;
  const int lq = l >> 4;

  float4v acc[8];
  #pragma unroll
  for (int j = 0; j < 8; j++) acc[j] = (float4v)(0.f);

  const unsigned short* Arow = A + (wv * 16 + lm) * 136 + lq * 8;
  #pragma unroll
  for (int ks = 0; ks < 4; ks++) {
    short8 af = *(const short8*)(Arow + ks * 32);
    #pragma unroll
    for (int j = 0; j < 8; j++) {
      short8 bf = *(const short8*)(Bt + (j * 16 + lm) * 136 + lq * 8 + ks * 32);
      acc[j] = __builtin_amdgcn_mfma_f32_16x16x32_bf16(af, bf, acc[j], 0, 0, 0);
    }
  }
  __syncthreads();   // done reading A/Bt; reuse as C

  #pragma unroll
  for (int j = 0; j < 8; j++) {
    int col = j * 16 + lm;
    int rbase = wv * 16 + lq * 4;
    #pragma unroll
    for (int r = 0; r < 4; r++) C[(rbase + r) * 132 + col] = acc[j][r];
  }
  __syncthreads();

  {
    #pragma unroll
    for (int i = 0; i < 4; i++) {
      int idx = tid + i * 256;
      int slice = idx >> 9;
      int r = (idx >> 3) & 63;
      int ch = idx & 7;
      int gr = row0 + r;
      if (gr < M) {
        float d = dis[gr];
        const float* cp = C + r * 132 + slice * 64 + ch * 8;
        uint4 u;
        u.x = pack2bf(cp[0] * d, cp[1] * d);
        u.y = pack2bf(cp[2] * d, cp[3] * d);
        u.z = pack2bf(cp[4] * d, cp[5] * d);
        u.w = pack2bf(cp[6] * d, cp[7] * d);
        *(uint4*)(hs16 + (size_t)slice * ((size_t)NNP * 64) + (size_t)gr * 64 + ch * 8) = u;
      }
    }
  }
}

// ---------------- MFMA GEMM 128->128 with fused BN(fold)/ReLU/residual input ----------------
// O is packed bf16 (128/row); Xin is fp32 (original x). Writes XA as bf16.

__global__ __launch_bounds__(256) void k_gemm128f(const unsigned short* __restrict__ O16,
                                                  const float* __restrict__ Xin,
                                                  unsigned short* __restrict__ XA16,
                                                  const float* __restrict__ gstat,
                                                  const float* __restrict__ g,
                                                  const float* __restrict__ be,
                                                  const unsigned short* __restrict__ Wt,
                                                  const float* __restrict__ dis,
                                                  unsigned short* __restrict__ hs16, int M) {
  __shared__ char smem[52224];
  __shared__ float bnabS[256];
  unsigned short* A  = (unsigned short*)smem;            // [64][136]
  unsigned short* Bt = (unsigned short*)(smem + 17408);  // [128][136]
  float* C = (float*)smem;                               // [64][132] (reuse after compute)
  const int tid = threadIdx.x;
  const int row0 = blockIdx.x * 64;

  bn_fold(gstat, g, be, bnabS, tid);
  __syncthreads();

  // stage A fused: thread t -> 8-feat chunk c=t&15, rows (t>>4)+i*16
  {
    int c = tid & 15;
    float4 alo = *(const float4*)(bnabS + c * 8);
    float4 ahi = *(const float4*)(bnabS + c * 8 + 4);
    float4 clo = *(const float4*)(bnabS + 128 + c * 8);
    float4 chi = *(const float4*)(bnabS + 128 + c * 8 + 4);
    #pragma unroll
    for (int i = 0; i < 4; i++) {
      int r = (tid >> 4) + i * 16;
      int gr = row0 + r;
      uint4 u = make_uint4(0u, 0u, 0u, 0u);
      if (gr < M) {
        uint4 ou = *(const uint4*)(O16 + (size_t)gr * 128 + c * 8);
        float4 xlo = *(const float4*)(Xin + (size_t)gr * 128 + c * 8);
        float4 xhi = *(const float4*)(Xin + (size_t)gr * 128 + c * 8 + 4);
        float v0 = fmaxf(bflo(ou.x) * alo.x + clo.x, 0.f) + xlo.x;
        float v1 = fmaxf(bfhi(ou.x) * alo.y + clo.y, 0.f) + xlo.y;
        float v2 = fmaxf(bflo(ou.y) * alo.z + clo.z, 0.f) + xlo.z;
        float v3 = fmaxf(bfhi(ou.y) * alo.w + clo.w, 0.f) + xlo.w;
        float v4 = fmaxf(bflo(ou.z) * ahi.x + chi.x, 0.f) + xhi.x;
        float v5 = fmaxf(bfhi(ou.z) * ahi.y + chi.y, 0.f) + xhi.y;
        float v6 = fmaxf(bflo(ou.w) * ahi.z + chi.z, 0.f) + xhi.z;
        float v7 = fmaxf(bfhi(ou.w) * ahi.w + chi.w, 0.f) + xhi.w;
        u.x = pack2bf(v0, v1);
        u.y = pack2bf(v2, v3);
        u.z = pack2bf(v4, v5);
        u.w = pack2bf(v6, v7);
        *(uint4*)(XA16 + (size_t)gr * 128 + c * 8) = u;
      }
      *(uint4*)(A + r * 136 + c * 8) = u;
    }
  }
  // stage Bt
  {
    int r = tid >> 1, h = (tid & 1) * 64;
    const uint4* src = (const uint4*)(Wt + r * 128 + h);
    uint4* dst = (uint4*)(Bt + r * 136 + h);
    #pragma unroll
    for (int i = 0; i < 8; i++) dst[i] = src[i];
  }
  __syncthreads();

  const int wv = tid >> 6;
  const int l = tid & 63;
  const int lm = l & 15;
  const int lq = l >> 4;

  float4v acc[8];
  #pragma unroll
  for (int j = 0; j < 8; j++) acc[j] = (float4v)(0.f);

  const unsigned short* Arow = A + (wv * 16 + lm) * 136 + lq * 8;
  #pragma unroll
  for (int ks = 0; ks < 4; ks++) {
    short8 af = *(const short8*)(Arow + ks * 32);
    #pragma unroll
    for (int j = 0; j < 8; j++) {
      short8 bf = *(const short8*)(Bt + (j * 16 + lm) * 136 + lq * 8 + ks * 32);
      acc[j] = __builtin_amdgcn_mfma_f32_16x16x32_bf16(af, bf, acc[j], 0, 0, 0);
    }
  }
  __syncthreads();

  #pragma unroll
  for (int j = 0; j < 8; j++) {
    int col = j * 16 + lm;
    int rbase = wv * 16 + lq * 4;
    #pragma unroll
    for (int r = 0; r < 4; r++) C[(rbase + r) * 132 + col] = acc[j][r];
  }
  __syncthreads();

  // pack-out: wave-linear
  {
    #pragma unroll
    for (int i = 0; i < 4; i++) {
      int idx = tid + i * 256;
      int slice = idx >> 9;
      int r = (idx >> 3) & 63;
      int ch = idx & 7;
      int gr = row0 + r;
      if (gr < M) {
        float d = dis[gr];
        const float* cp = C + r * 132 + slice * 64 + ch * 8;
        uint4 u;
        u.x = pack2bf(cp[0] * d, cp[1] * d);
        u.y = pack2bf(cp[2] * d, cp[3] * d);
        u.z = pack2bf(cp[4] * d, cp[5] * d);
        u.w = pack2bf(cp[6] * d, cp[7] * d);
        *(uint4*)(hs16 + (size_t)slice * ((size_t)NNP * 64) + (size_t)gr * 64 + ch * 8) = u;
      }
    }
  }
}

// ---------------- MFMA bf16 GEMM 128->32 with fused BN(fold)/ReLU/residual input ----------------

__global__ __launch_bounds__(256) void k_gemm32mf(const unsigned short* __restrict__ O16,
                                                  const unsigned short* __restrict__ XA16,
                                                  const float* __restrict__ gstat,
                                                  const float* __restrict__ g,
                                                  const float* __restrict__ be,
                                                  const unsigned short* __restrict__ Wt2,
                                                  const float* __restrict__ dis,
                                                  float* __restrict__ H, int M) {
  __shared__ char smem[26112];
  __shared__ float bnabS[256];
  unsigned short* A   = (unsigned short*)smem;            // [64][136]
  unsigned short* Bt2 = (unsigned short*)(smem + 17408);  // [32][136]
  float* C = (float*)smem;                                // [64][36] (reuse)
  const int tid = threadIdx.x;
  const int row0 = blockIdx.x * 64;

  bn_fold(gstat, g, be, bnabS, tid);
  __syncthreads();

  // stage A fused: bf16 O + bf16 residual
  {
    int c = tid & 15;
    float4 alo = *(const float4*)(bnabS + c * 8);
    float4 ahi = *(const float4*)(bnabS + c * 8 + 4);
    float4 clo = *(const float4*)(bnabS + 128 + c * 8);
    float4 chi = *(const float4*)(bnabS + 128 + c * 8 + 4);
    #pragma unroll
    for (int i = 0; i < 4; i++) {
      int r = (tid >> 4) + i * 16;
      int gr = row0 + r;
      uint4 u = make_uint4(0u, 0u, 0u, 0u);
      if (gr < M) {
        uint4 ou = *(const uint4*)(O16 + (size_t)gr * 128 + c * 8);
        uint4 xu = *(const uint4*)(XA16 + (size_t)gr * 128 + c * 8);
        float v0 = fmaxf(bflo(ou.x) * alo.x + clo.x, 0.f) + bflo(xu.x);
        float v1 = fmaxf(bfhi(ou.x) * alo.y + clo.y, 0.f) + bfhi(xu.x);
        float v2 = fmaxf(bflo(ou.y) * alo.z + clo.z, 0.f) + bflo(xu.y);
        float v3 = fmaxf(bfhi(ou.y) * alo.w + clo.w, 0.f) + bfhi(xu.y);
        float v4 = fmaxf(bflo(ou.z) * ahi.x + chi.x, 0.f) + bflo(xu.z);
        float v5 = fmaxf(bfhi(ou.z) * ahi.y + chi.y, 0.f) + bfhi(xu.z);
        float v6 = fmaxf(bflo(ou.w) * ahi.z + chi.z, 0.f) + bflo(xu.w);
        float v7 = fmaxf(bfhi(ou.w) * ahi.w + chi.w, 0.f) + bfhi(xu.w);
        u.x = pack2bf(v0, v1);
        u.y = pack2bf(v2, v3);
        u.z = pack2bf(v4, v5);
        u.w = pack2bf(v6, v7);
      }
      *(uint4*)(A + r * 136 + c * 8) = u;
    }
  }
  // stage Bt2: thread t -> row t>>3 (0..31), 16 bf16 at (t&7)*16 = 2 x uint4
  {
    int r = tid >> 3, h = (tid & 7) * 16;
    const uint4* src = (const uint4*)(Wt2 + r * 128 + h);
    uint4* dst = (uint4*)(Bt2 + r * 136 + h);
    dst[0] = src[0];
    dst[1] = src[1];
  }
  __syncthreads();

  const int wv = tid >> 6;
  const int l = tid & 63;
  const int lm = l & 15;
  const int lq = l >> 4;

  float4v acc[2];
  acc[0] = (float4v)(0.f);
  acc[1] = (float4v)(0.f);

  const unsigned short* Arow = A + (wv * 16 + lm) * 136 + lq * 8;
  #pragma unroll
  for (int ks = 0; ks < 4; ks++) {
    short8 af = *(const short8*)(Arow + ks * 32);
    #pragma unroll
    for (int j = 0; j < 2; j++) {
      short8 bf = *(const short8*)(Bt2 + (j * 16 + lm) * 136 + lq * 8 + ks * 32);
      acc[j] = __builtin_amdgcn_mfma_f32_16x16x32_bf16(af, bf, acc[j], 0, 0, 0);
    }
  }
  __syncthreads();   // reuse smem as C

  #pragma unroll
  for (int j = 0; j < 2; j++) {
    int col = j * 16 + lm;
    int rbase = wv * 16 + lq * 4;
    #pragma unroll
    for (int r = 0; r < 4; r++) C[(rbase + r) * 36 + col] = acc[j][r];
  }
  __syncthreads();

  // pack-out: wave-linear float4 over [64 rows][8 float4]
  {
    #pragma unroll
    for (int i = 0; i < 2; i++) {
      int idx = tid + i * 256;
      int r = idx >> 3;
      int ch = idx & 7;
      int gr = row0 + r;
      if (gr < M) {
        float d = dis[gr];
        const float* cp = C + r * 36 + ch * 4;
        float4 v = make_float4(cp[0] * d, cp[1] * d, cp[2] * d, cp[3] * d);
        *(float4*)(H + (size_t)gr * 32 + ch * 4) = v;
      }
    }
  }
}

// ---------------- aggregation layer 0/1: both slices per wave, 8 nodes/wave ----------------
// R5-proven shape: 16 gathers in flight per lane, csr prefetched one iteration
// ahead, low-VGPR class (do NOT unroll 2x: R6 showed 132 VGPR -> occupancy collapse).
// Padding handled by degtot masking: positions >= e0+deg redirect to zero pad row NN.
// Output packed bf16. Fused BN stats via LDS + 8-way replicated atomics.

__global__ __launch_bounds__(256) void k_agg128s(const unsigned short* __restrict__ Hs,
                                                 const float* __restrict__ dis,
                                                 const int* __restrict__ rowstart,
                                                 const int* __restrict__ degtot,
                                                 const int* __restrict__ csr_src,
                                                 const float* __restrict__ bias,
                                                 unsigned short* __restrict__ out16,
                                                 float* __restrict__ gstat) {
  __shared__ float smS[4][128], smQ[4][128];
  const int tid = threadIdx.x;
  const int wv = tid >> 6;
  const int lane = tid & 63;
  const int node_sub = lane >> 3;   // 0..7
  const int fl = lane & 7;          // 0..7 (8 bf16 = 16 B each)
  const int base = node_sub * 8;
  const int w = blockIdx.x * 32 + wv * 8 + node_sub;
  const bool act = w < NN;
  const unsigned short* __restrict__ S0 = Hs + fl * 8;
  const unsigned short* __restrict__ S1 = Hs + (size_t)NNP * 64 + fl * 8;
  float di = act ? dis[w] : 0.f;
  int e0 = 0, e1 = 0, dend = 0;
  if (act) { e0 = rowstart[w]; e1 = rowstart[w + 1]; dend = e0 + degtot[w]; }

  float a0[8], a1[8];
  #pragma unroll
  for (int j = 0; j < 8; j++) { a0[j] = 0.f; a1[j] = 0.f; }

  int idxCur = (e0 < e1) ? csr_src[e0 + fl] : 0;
  for (int e = e0; e < e1; e += 8) {
    int cur = (e + fl < dend) ? idxCur : (int)NN;   // pad -> zero row
    if (e + 8 < e1) idxCur = csr_src[e + 8 + fl];
    int s0 = __shfl(cur, base + 0), s1 = __shfl(cur, base + 1);
    int s2 = __shfl(cur, base + 2), s3 = __shfl(cur, base + 3);
    int s4 = __shfl(cur, base + 4), s5 = __shfl(cur, base + 5);
    int s6 = __shfl(cur, base + 6), s7 = __shfl(cur, base + 7);
    uint4 g0 = *(const uint4*)(S0 + (size_t)s0 * 64);
    uint4 g1 = *(const uint4*)(S0 + (size_t)s1 * 64);
    uint4 g2 = *(const uint4*)(S0 + (size_t)s2 * 64);
    uint4 g3 = *(const uint4*)(S0 + (size_t)s3 * 64);
    uint4 g4 = *(const uint4*)(S0 + (size_t)s4 * 64);
    uint4 g5 = *(const uint4*)(S0 + (size_t)s5 * 64);
    uint4 g6 = *(const uint4*)(S0 + (size_t)s6 * 64);
    uint4 g7 = *(const uint4*)(S0 + (size_t)s7 * 64);
    uint4 h0 = *(const uint4*)(S1 + (size_t)s0 * 64);
    uint4 h1 = *(const uint4*)(S1 + (size_t)s1 * 64);
    uint4 h2 = *(const uint4*)(S1 + (size_t)s2 * 64);
    uint4 h3 = *(const uint4*)(S1 + (size_t)s3 * 64);
    uint4 h4 = *(const uint4*)(S1 + (size_t)s4 * 64);
    uint4 h5 = *(const uint4*)(S1 + (size_t)s5 * 64);
    uint4 h6 = *(const uint4*)(S1 + (size_t)s6 * 64);
    uint4 h7 = *(const uint4*)(S1 + (size_t)s7 * 64);
    a0[0] += ((bflo(g0.x) + bflo(g1.x)) + (bflo(g2.x) + bflo(g3.x))) + ((bflo(g4.x) + bflo(g5.x)) + (bflo(g6.x) + bflo(g7.x)));
    a0[1] += ((bfhi(g0.x) + bfhi(g1.x)) + (bfhi(g2.x) + bfhi(g3.x))) + ((bfhi(g4.x) + bfhi(g5.x)) + (bfhi(g6.x) + bfhi(g7.x)));
    a0[2] += ((bflo(g0.y) + bflo(g1.y)) + (bflo(g2.y) + bflo(g3.y))) + ((bflo(g4.y) + bflo(g5.y)) + (bflo(g6.y) + bflo(g7.y)));
    a0[3] += ((bfhi(g0.y) + bfhi(g1.y)) + (bfhi(g2.y) + bfhi(g3.y))) + ((bfhi(g4.y) + bfhi(g5.y)) + (bfhi(g6.y) + bfhi(g7.y)));
    a0[4] += ((bflo(g0.z) + bflo(g1.z)) + (bflo(g2.z) + bflo(g3.z))) + ((bflo(g4.z) + bflo(g5.z)) + (bflo(g6.z) + bflo(g7.z)));
    a0[5] += ((bfhi(g0.z) + bfhi(g1.z)) + (bfhi(g2.z) + bfhi(g3.z))) + ((bfhi(g4.z) + bfhi(g5.z)) + (bfhi(g6.z) + bfhi(g7.z)));
    a0[6] += ((bflo(g0.w) + bflo(g1.w)) + (bflo(g2.w) + bflo(g3.w))) + ((bflo(g4.w) + bflo(g5.w)) + (bflo(g6.w) + bflo(g7.w)));
    a0[7] += ((bfhi(g0.w) + bfhi(g1.w)) + (bfhi(g2.w) + bfhi(g3.w))) + ((bfhi(g4.w) + bfhi(g5.w)) + (bfhi(g6.w) + bfhi(g7.w)));
    a1[0] += ((bflo(h0.x) + bflo(h1.x)) + (bflo(h2.x) + bflo(h3.x))) + ((bflo(h4.x) + bflo(h5.x)) + (bflo(h6.x) + bflo(h7.x)));
    a1[1] += ((bfhi(h0.x) + bfhi(h1.x)) + (bfhi(h2.x) + bfhi(h3.x))) + ((bfhi(h4.x) + bfhi(h5.x)) + (bfhi(h6.x) + bfhi(h7.x)));
    a1[2] += ((bflo(h0.y) + bflo(h1.y)) + (bflo(h2.y) + bflo(h3.y))) + ((bflo(h4.y) + bflo(h5.y)) + (bflo(h6.y) + bflo(h7.y)));
    a1[3] += ((bfhi(h0.y) + bfhi(h1.y)) + (bfhi(h2.y) + bfhi(h3.y))) + ((bfhi(h4.y) + bfhi(h5.y)) + (bfhi(h6.y) + bfhi(h7.y)));
    a1[4] += ((bflo(h0.z) + bflo(h1.z)) + (bflo(h2.z) + bflo(h3.z))) + ((bflo(h4.z) + bflo(h5.z)) + (bflo(h6.z) + bflo(h7.z)));
    a1[5] += ((bfhi(h0.z) + bfhi(h1.z)) + (bfhi(h2.z) + bfhi(h3.z))) + ((bfhi(h4.z) + bfhi(h5.z)) + (bfhi(h6.z) + bfhi(h7.z)));
    a1[6] += ((bflo(h0.w) + bflo(h1.w)) + (bflo(h2.w) + bflo(h3.w))) + ((bflo(h4.w) + bflo(h5.w)) + (bflo(h6.w) + bflo(h7.w)));
    a1[7] += ((bfhi(h0.w) + bfhi(h1.w)) + (bfhi(h2.w) + bfhi(h3.w))) + ((bfhi(h4.w) + bfhi(h5.w)) + (bfhi(h6.w) + bfhi(h7.w)));
  }

  float rv0[8], rv1[8];
  if (act) {
    uint4 sv0 = *(const uint4*)(S0 + (size_t)w * 64);
    uint4 sv1 = *(const uint4*)(S1 + (size_t)w * 64);
    float se0[8] = { bflo(sv0.x), bfhi(sv0.x), bflo(sv0.y), bfhi(sv0.y),
                     bflo(sv0.z), bfhi(sv0.z), bflo(sv0.w), bfhi(sv0.w) };
    float se1[8] = { bflo(sv1.x), bfhi(sv1.x), bflo(sv1.y), bfhi(sv1.y),
                     bflo(sv1.z), bfhi(sv1.z), bflo(sv1.w), bfhi(sv1.w) };
    #pragma unroll
    for (int j = 0; j < 8; j++) {
      rv0[j] = (a0[j] + se0[j]) * di + bias[fl * 8 + j];
      rv1[j] = (a1[j] + se1[j]) * di + bias[64 + fl * 8 + j];
    }
    uint4 u0, u1;
    u0.x = pack2bf(rv0[0], rv0[1]); u0.y = pack2bf(rv0[2], rv0[3]);
    u0.z = pack2bf(rv0[4], rv0[5]); u0.w = pack2bf(rv0[6], rv0[7]);
    u1.x = pack2bf(rv1[0], rv1[1]); u1.y = pack2bf(rv1[2], rv1[3]);
    u1.z = pack2bf(rv1[4], rv1[5]); u1.w = pack2bf(rv1[6], rv1[7]);
    *(uint4*)(out16 + (size_t)w * 128 + fl * 8)      = u0;
    *(uint4*)(out16 + (size_t)w * 128 + 64 + fl * 8) = u1;
  } else {
    #pragma unroll
    for (int j = 0; j < 8; j++) { rv0[j] = 0.f; rv1[j] = 0.f; }
  }

  // fused BN stats: reduce over node_sub (lane bits 3..5), then cross-wave via LDS
  float q0[8], q1[8];
  #pragma unroll
  for (int j = 0; j < 8; j++) { q0[j] = rv0[j] * rv0[j]; q1[j] = rv1[j] * rv1[j]; }
  #pragma unroll
  for (int off = 8; off <= 32; off <<= 1) {
    #pragma unroll
    for (int j = 0; j < 8; j++) {
      rv0[j] += __shfl_xor(rv0[j], off);
      q0[j]  += __shfl_xor(q0[j], off);
      rv1[j] += __shfl_xor(rv1[j], off);
      q1[j]  += __shfl_xor(q1[j], off);
    }
  }
  if (node_sub == 0) {
    #pragma unroll
    for (int j = 0; j < 8; j++) {
      smS[wv][fl * 8 + j] = rv0[j];      smQ[wv][fl * 8 + j] = q0[j];
      smS[wv][64 + fl * 8 + j] = rv1[j]; smQ[wv][64 + fl * 8 + j] = q1[j];
    }
  }
  __syncthreads();
  if (tid < 128) {
    float s = (smS[0][tid] + smS[1][tid]) + (smS[2][tid] + smS[3][tid]);
    float q = (smQ[0][tid] + smQ[1][tid]) + (smQ[2][tid] + smQ[3][tid]);
    int rep = blockIdx.x & 7;
    atomicAdd(&gstat[rep * 256 + tid], s);
    atomicAdd(&gstat[rep * 256 + 128 + tid], q);
  }
}

// ---------------- final layer: aggregation + fused log_softmax (fp32) ----------------
// Same degtot masking for padding.

__global__ __launch_bounds__(256) void k_agg32lsm(const float* __restrict__ H2,
                                                  const float* __restrict__ dis,
                                                  const int* __restrict__ rowstart,
                                                  const int* __restrict__ degtot,
                                                  const int* __restrict__ csr_src,
                                                  const float* __restrict__ bias,
                                                  float* __restrict__ out) {
  int wave = (blockIdx.x * 256 + threadIdx.x) >> 6;
  int lane = threadIdx.x & 63;
  int half = lane >> 5;
  int l = lane & 31;
  int hbase = half * 32;
  int w = wave * 2 + half;
  if (w >= NN) return;   // NN even: both halves exit together
  const float* __restrict__ S = H2 + l;
  float di = dis[w];
  int e0 = rowstart[w], e1 = rowstart[w + 1];
  int dend = e0 + degtot[w];
  float acc = 0.f;
  for (int e = e0; e < e1; e += 8) {
    int myIdx = csr_src[e + (l & 7)];
    if (e + (l & 7) >= dend) myIdx = NN;   // pad -> zero row
    int s0 = __shfl(myIdx, hbase + 0), s1 = __shfl(myIdx, hbase + 1);
    int s2 = __shfl(myIdx, hbase + 2), s3 = __shfl(myIdx, hbase + 3);
    int s4 = __shfl(myIdx, hbase + 4), s5 = __shfl(myIdx, hbase + 5);
    int s6 = __shfl(myIdx, hbase + 6), s7 = __shfl(myIdx, hbase + 7);
    float h0 = S[(size_t)s0 * 32], h1 = S[(size_t)s1 * 32];
    float h2v = S[(size_t)s2 * 32], h3 = S[(size_t)s3 * 32];
    float h4 = S[(size_t)s4 * 32], h5 = S[(size_t)s5 * 32];
    float h6 = S[(size_t)s6 * 32], h7 = S[(size_t)s7 * 32];
    acc += ((h0 + h1) + (h2v + h3)) + ((h4 + h5) + (h6 + h7));
  }
  float v = (acc + S[(size_t)w * 32]) * di + bias[l];
  float m = v;
  #pragma unroll
  for (int off = 16; off >= 1; off >>= 1) m = fmaxf(m, __shfl_xor(m, off));
  float ex = expf(v - m);
  float s = ex;
  #pragma unroll
  for (int off = 16; off >= 1; off >>= 1) s += __shfl_xor(s, off);
  out[(size_t)w * 32 + l] = v - m - logf(s);
}

// ---------------- launch ----------------

extern "C" void kernel_launch(void* const* d_in, const int* in_sizes, int n_in,
                              void* d_out, int out_size, void* d_ws, size_t ws_size,
                              hipStream_t stream) {
  const float* x   = (const float*)d_in[0];
  const int*   ei  = (const int*)d_in[1];
  const float* W0  = (const float*)d_in[2];
  const float* b0  = (const float*)d_in[3];
  const float* g0  = (const float*)d_in[4];
  const float* be0 = (const float*)d_in[5];
  const float* W1  = (const float*)d_in[6];
  const float* b1  = (const float*)d_in[7];
  const float* g1  = (const float*)d_in[8];
  const float* be1 = (const float*)d_in[9];
  const float* W2  = (const float*)d_in[10];
  const float* b2  = (const float*)d_in[11];
  float* out = (float*)d_out;
  const int* srcI = ei;
  const int* dstI = ei + NE;

  char* p = (char*)d_ws;
  auto take = [&](size_t bytes) { char* r = p; p += (bytes + 255) & ~(size_t)255; return (void*)r; };
  int*   deg      = (int*)take(NN * 4);
  int*   degtot   = (int*)take(NN * 4);
  int*   rowstart = (int*)take((NN + 1) * 4);
  int*   blksum   = (int*)take(64 * 4);
  int*   binCnt   = (int*)take(8 * 4);
  float* dis      = (float*)take(NN * 4);
  int*   csr      = (int*)take((size_t)NEP * 4);
  int2*  bin      = (int2*)take((size_t)NBKT * BCAP * 8);
  float* gstat    = (float*)take(4096 * 4);  // 2 layers x 8 reps x 256
  unsigned short* wt16 = (unsigned short*)take((2 * 16384 + 4096) * 2);  // W0^T, W1^T, W2^T bf16
  unsigned short* hs16 = (unsigned short*)take((size_t)NNP * 128 * 2);   // bf16, 2-slice-major
  unsigned short* o16  = (unsigned short*)take((size_t)NN * 128 * 2);    // agg output, packed bf16
  unsigned short* xA16 = (unsigned short*)take((size_t)NN * 128 * 2);    // layer-1 input, packed bf16
  float* h2       = (float*)take((size_t)NNP * 32 * 4);

  k_init<<<(NN + 255) / 256, 256, 0, stream>>>(deg, gstat, binCnt, W0, W1, W2, wt16);
  k_binA<<<(NE + 1023) / 1024, 1024, 0, stream>>>(srcI, dstI, deg, binCnt, bin);
  k_scan1<<<NBLK, 1024, 0, stream>>>(deg, degtot, rowstart, blksum);
  k_scan3<<<(NN + 255) / 256, 256, 0, stream>>>(rowstart, blksum, degtot, dis, hs16, h2);

  const int aggGrid = (NN + 31) / 32;   // 8 nodes/wave, both slices, 4 waves/block
  const int aggGrid32 = (NN + 7) / 8;   // 2 nodes/wave

  // ---- layer 0: atomic-free csr scatter + GEMM in one dispatch (spatial split) ----
  k_fillgemm<<<FILLBLK + GEMMBLK, 256, 0, stream>>>(bin, binCnt, rowstart, csr, x, wt16, dis, hs16);
  k_agg128s<<<aggGrid, 256, 0, stream>>>(hs16, dis, rowstart, degtot, csr, b0, o16, gstat);

  // ---- layer 1 (BN finalize + BN/ReLU/residual fused into GEMM stage-A) ----
  k_gemm128f<<<(NN + 63) / 64, 256, 0, stream>>>(o16, x, xA16, gstat, g0, be0,
                                                 wt16 + 16384, dis, hs16, NN);
  k_agg128s<<<aggGrid, 256, 0, stream>>>(hs16, dis, rowstart, degtot, csr, b1, o16, gstat + 2048);

  // ---- final conv (BN finalize + fuse in-kernel, xB never materialized) ----
  k_gemm32mf<<<(NN + 63) / 64, 256, 0, stream>>>(o16, xA16, gstat + 2048, g1, be1,
                                                 wt16 + 32768, dis, h2, NN);
  k_agg32lsm<<<aggGrid32, 256, 0, stream>>>(h2, dis, rowstart, degtot, csr, b2, out);
}